// Round 8
// baseline (36.732 us; speedup 1.0000x reference)
//
#include <hip/hip_runtime.h>
#include <math.h>

#define B_ 4
#define T_ 512
#define D_ 2048
#define H_ 1024
#define E_ 2
#define DC_ 32          // d-chunk width in k_part
#define NDC_ 64         // D_/DC_

#define LD4(p) (*reinterpret_cast<const float4*>(p))

// Lessons (measured, this session):
//  R2: __threadfence => buffer_wbl2/inv cache maintenance, +38us. Never.
//  R4: spinning on an RMW'd line => ownership ping-pong, ~20us/barrier. Never.
//  R5: 512 same-line fetch_adds serialize (~15ns each), +7us. Never.
//  R6: even polite store-array grid barriers cost ~17us. => fusion only when
//      it needs NO sync: split-d partials materialized to ws (this file).

__device__ __forceinline__ float waveReduceSum(float v) {
    #pragma unroll
    for (int o = 32; o > 0; o >>= 1) v += __shfl_down(v, o, 64);
    return v;
}

// N1: w2s[row] = sum_d W2[row,d], row = e*H+h. 2 rows per wave, 256 blocks.
__global__ __launch_bounds__(256) void k_w2sum(const float* __restrict__ W2,
                                               float* __restrict__ w2s) {
    int gw   = (blockIdx.x * 256 + threadIdx.x) >> 6;   // 0..1023
    int lane = threadIdx.x & 63;
    const float* p0 = W2 + (size_t)(2 * gw) * D_;
    const float* p1 = p0 + D_;
    float a0 = 0.f, a1 = 0.f;
    #pragma unroll
    for (int k = 0; k < D_ / 256; ++k) {                // 8 float4 per lane per row
        float4 u = LD4(p0 + (lane + k * 64) * 4);
        float4 w = LD4(p1 + (lane + k * 64) * 4);
        a0 += (u.x + u.y) + (u.z + u.w);
        a1 += (w.x + w.y) + (w.z + w.w);
    }
    #pragma unroll
    for (int o = 32; o > 0; o >>= 1) {
        a0 += __shfl_down(a0, o, 64);
        a1 += __shfl_down(a1, o, 64);
    }
    if (lane == 0) {
        w2s[2 * gw]     = a0;
        w2s[2 * gw + 1] = a1;
    }
}

// N2: block = (e, dc, token-half).  Phase A: v_loc[32] = W1[e, dc-rows, :] . w2s[e,:]
// and wg_loc[32] = Wg[dc-rows, e].  Phase B: for 1024 tokens, partial dots over the
// 32-column x slice -> A[e][dc][bt], G[e][dc][bt].  No atomics, buffers fully
// overwritten every call.
__global__ __launch_bounds__(256) void k_part(const float* __restrict__ W1,
                                              const float* __restrict__ Wg,
                                              const float* __restrict__ x,
                                              const float* __restrict__ w2s,
                                              float* __restrict__ A,
                                              float* __restrict__ G) {
    __shared__ float lv[DC_], lw[DC_];
    int e    = blockIdx.x >> 7;                         // 0..1
    int dc   = (blockIdx.x >> 1) & 63;                  // 0..63
    int half = blockIdx.x & 1;                          // 0..1
    int tid  = threadIdx.x;
    int lane = tid & 63, wid = tid >> 6;

    const float* w = w2s + e * H_;
    #pragma unroll
    for (int r = 0; r < 8; ++r) {                       // wave wid does rows wid*8..wid*8+7
        int j = wid * 8 + r;
        const float* p = W1 + ((size_t)e * D_ + dc * DC_ + j) * H_;
        float acc = 0.f;
        #pragma unroll
        for (int k = 0; k < H_ / 256; ++k) {            // 4 float4 per lane
            float4 a = LD4(p + (lane + k * 64) * 4);
            float4 b = LD4(w + (lane + k * 64) * 4);
            acc += a.x * b.x + a.y * b.y + a.z * b.z + a.w * b.w;
        }
        acc = waveReduceSum(acc);
        if (lane == 0) lv[j] = acc;
    }
    if (tid < DC_) lw[tid] = Wg[(dc * DC_ + tid) * E_ + e];
    __syncthreads();

    float* Arow = A + ((size_t)e * NDC_ + dc) * (B_ * T_);
    float* Grow = G + ((size_t)e * NDC_ + dc) * (B_ * T_);
    #pragma unroll 2
    for (int r = 0; r < 4; ++r) {
        int bt = half * 1024 + r * 256 + tid;
        const float* xp = x + (size_t)bt * D_ + dc * DC_;   // 128B aligned slice
        float z = 0.f, g = 0.f;
        #pragma unroll
        for (int q = 0; q < 8; ++q) {
            float4 xv = LD4(xp + q * 4);
            z += xv.x * lv[q*4+0] + xv.y * lv[q*4+1] + xv.z * lv[q*4+2] + xv.w * lv[q*4+3];
            g += xv.x * lw[q*4+0] + xv.y * lw[q*4+1] + xv.z * lw[q*4+2] + xv.w * lw[q*4+3];
        }
        Arow[bt] = z;                                    // coalesced across tid
        Grow[bt] = g;
    }
}

// N3: 4 blocks (one per batch) x 512 threads (one per token).  Sum the 64 partials
// per (e), compute c[e] in-block from b1/b2/w2s, gate/argmax/combine, then the
// per-batch log_softmax in-block.  Replaces k_token's s-write + k_lsm node.
__global__ __launch_bounds__(512) void k_comb(const float* __restrict__ A,
                                              const float* __restrict__ G,
                                              const float* __restrict__ w2s,
                                              const float* __restrict__ b1,
                                              const float* __restrict__ b2,
                                              float* __restrict__ out) {
    __shared__ float red[8];
    __shared__ float cc[E_];
    int b = blockIdx.x, tid = threadIdx.x;
    int lane = tid & 63, wid = tid >> 6;

    #pragma unroll
    for (int e = 0; e < E_; ++e) {                      // c[e] = b1.w2s + sum(b2)
        float acc = 0.f;
        for (int i = tid; i < H_; i += 512) acc += b1[e * H_ + i] * w2s[e * H_ + i];
        for (int i = tid; i < D_; i += 512) acc += b2[e * D_ + i];
        acc = waveReduceSum(acc);
        if (lane == 0) red[wid] = acc;
        __syncthreads();
        if (tid == 0) {
            float t = 0.f;
            #pragma unroll
            for (int w2 = 0; w2 < 8; ++w2) t += red[w2];
            cc[e] = t;
        }
        __syncthreads();
    }

    int bt = b * T_ + tid;
    float z0 = 0.f, z1 = 0.f, g0 = 0.f, g1 = 0.f;
    #pragma unroll 8
    for (int dc = 0; dc < NDC_; ++dc) {                 // coalesced: lane-consecutive bt
        z0 += A[(size_t)(0 * NDC_ + dc) * (B_ * T_) + bt];
        z1 += A[(size_t)(1 * NDC_ + dc) * (B_ * T_) + bt];
        g0 += G[(size_t)(0 * NDC_ + dc) * (B_ * T_) + bt];
        g1 += G[(size_t)(1 * NDC_ + dc) * (B_ * T_) + bt];
    }
    int e = (g1 > g0) ? 1 : 0;                          // argmax, first index on tie
    float m0 = fmaxf(g0, g1);
    float p0 = expf(g0 - m0), p1 = expf(g1 - m0);
    float gate = ((e == 0) ? p0 : p1) / (p0 + p1);
    float val  = gate * (((e == 0) ? z0 : z1) + cc[e]);

    // per-batch log_softmax over the block's 512 values
    float m = val;
    #pragma unroll
    for (int o = 1; o < 64; o <<= 1) m = fmaxf(m, __shfl_xor(m, o, 64));
    if (lane == 0) red[wid] = m;
    __syncthreads();
    m = red[0];
    #pragma unroll
    for (int w2 = 1; w2 < 8; ++w2) m = fmaxf(m, red[w2]);
    __syncthreads();

    float sum = expf(val - m);
    #pragma unroll
    for (int o = 1; o < 64; o <<= 1) sum += __shfl_xor(sum, o, 64);
    if (lane == 0) red[wid] = sum;
    __syncthreads();
    sum = 0.f;
    #pragma unroll
    for (int w2 = 0; w2 < 8; ++w2) sum += red[w2];

    out[bt] = val - m - logf(sum);
}

extern "C" void kernel_launch(void* const* d_in, const int* in_sizes, int n_in,
                              void* d_out, int out_size, void* d_ws, size_t ws_size,
                              hipStream_t stream) {
    (void)in_sizes; (void)n_in; (void)out_size; (void)ws_size;
    const float* x  = (const float*)d_in[0];
    const float* Wg = (const float*)d_in[1];
    const float* W1 = (const float*)d_in[2];
    const float* b1 = (const float*)d_in[3];
    const float* W2 = (const float*)d_in[4];
    const float* b2 = (const float*)d_in[5];
    float* out = (float*)d_out;

    float* ws  = (float*)d_ws;
    float* w2s = ws;                        // [E,H]            2048 floats
    float* A   = ws + 2048;                 // [E][NDC][B*T]  262144 floats
    float* G   = ws + 2048 + 262144;        // [E][NDC][B*T]  262144 floats

    k_w2sum<<<256, 256, 0, stream>>>(W2, w2s);
    k_part <<<256, 256, 0, stream>>>(W1, Wg, x, w2s, A, G);
    k_comb <<<B_,  512, 0, stream>>>(A, G, w2s, b1, b2, out);
}

// Round 9
// 25.835 us; speedup vs baseline: 1.4218x; 1.4218x over previous
//
#include <hip/hip_runtime.h>
#include <math.h>

#define B_ 4
#define T_ 512
#define D_ 2048
#define H_ 1024
#define E_ 2

#define LD4(p) (*reinterpret_cast<const float4*>(p))

// Lessons (measured, this session):
//  R2: __threadfence => buffer_wbl2/inv cache maintenance, +38us. Never.
//  R4: spinning on an RMW'd line => ownership ping-pong, ~20us/barrier. Never.
//  R5: 512 same-line fetch_adds serialize (~15ns each), +7us. Never.
//  R6: even polite store-array grid barriers cost ~17us. No grid sync, period.
//  R8: splitting the x-pass into 32-float slivers (partials scheme) wrecks
//      coalescing on the dominant stream: +13.5us. Keep unit-stride fat rows.
//  => 4-node graph, one wave owns whole rows, maximize bytes/wave per node.

__device__ __forceinline__ float waveReduceSum(float v) {
    #pragma unroll
    for (int o = 32; o > 0; o >>= 1) v += __shfl_down(v, o, 64);
    return v;
}

// N1: w2s[row] = sum_d W2[row,d], row = e*H+h. 2 rows per wave, 256 blocks.
__global__ __launch_bounds__(256) void k_w2sum(const float* __restrict__ W2,
                                               float* __restrict__ w2s) {
    int gw   = (blockIdx.x * 256 + threadIdx.x) >> 6;   // 0..1023
    int lane = threadIdx.x & 63;
    const float* p0 = W2 + (size_t)(2 * gw) * D_;
    const float* p1 = p0 + D_;
    float a0 = 0.f, a1 = 0.f;
    #pragma unroll
    for (int k = 0; k < D_ / 256; ++k) {                // 8 float4 per lane per row
        float4 u = LD4(p0 + (lane + k * 64) * 4);
        float4 w = LD4(p1 + (lane + k * 64) * 4);
        a0 += (u.x + u.y) + (u.z + u.w);
        a1 += (w.x + w.y) + (w.z + w.w);
    }
    #pragma unroll
    for (int o = 32; o > 0; o >>= 1) {
        a0 += __shfl_down(a0, o, 64);
        a1 += __shfl_down(a1, o, 64);
    }
    if (lane == 0) {
        w2s[2 * gw]     = a0;
        w2s[2 * gw + 1] = a1;
    }
}

// N2: v[e,d] = sum_h W1[e,d,h]*w2s[e,h]. 4 rows per wave (row group 4-aligned,
// never straddles the expert boundary) -> w2s loads amortized 4x, 16 row-loads
// in flight. 256 blocks + 2 c-blocks.
__global__ __launch_bounds__(256) void k_vred(const float* __restrict__ W1,
                                              const float* __restrict__ w2s,
                                              const float* __restrict__ b1,
                                              const float* __restrict__ b2,
                                              float* __restrict__ v,
                                              float* __restrict__ c) {
    if (blockIdx.x >= 256) {
        __shared__ float lds[4];
        int e = blockIdx.x - 256;
        float acc = 0.f;
        for (int i = threadIdx.x; i < H_; i += 256) acc += b1[e * H_ + i] * w2s[e * H_ + i];
        for (int i = threadIdx.x; i < D_; i += 256) acc += b2[e * D_ + i];
        acc = waveReduceSum(acc);
        if ((threadIdx.x & 63) == 0) lds[threadIdx.x >> 6] = acc;
        __syncthreads();
        if (threadIdx.x == 0) c[e] = lds[0] + lds[1] + lds[2] + lds[3];
        return;
    }
    int gw   = (blockIdx.x * 256 + threadIdx.x) >> 6;   // 0..1023
    int lane = threadIdx.x & 63;
    int row0 = 4 * gw;                                  // 0..4092, 4-aligned
    int e    = row0 >> 11;                              // row / D_
    const float* p = W1 + (size_t)row0 * H_;
    const float* w = w2s + e * H_;
    float a0 = 0.f, a1 = 0.f, a2 = 0.f, a3 = 0.f;
    #pragma unroll
    for (int k = 0; k < H_ / 256; ++k) {                // 4 iters, 5 float4 each
        int i = (lane + k * 64) * 4;
        float4 wa = LD4(w + i);
        float4 u0 = LD4(p + i);
        float4 u1 = LD4(p + H_ + i);
        float4 u2 = LD4(p + 2 * H_ + i);
        float4 u3 = LD4(p + 3 * H_ + i);
        a0 += u0.x * wa.x + u0.y * wa.y + u0.z * wa.z + u0.w * wa.w;
        a1 += u1.x * wa.x + u1.y * wa.y + u1.z * wa.z + u1.w * wa.w;
        a2 += u2.x * wa.x + u2.y * wa.y + u2.z * wa.z + u2.w * wa.w;
        a3 += u3.x * wa.x + u3.y * wa.y + u3.z * wa.z + u3.w * wa.w;
    }
    #pragma unroll
    for (int o = 32; o > 0; o >>= 1) {
        a0 += __shfl_down(a0, o, 64);
        a1 += __shfl_down(a1, o, 64);
        a2 += __shfl_down(a2, o, 64);
        a3 += __shfl_down(a3, o, 64);
    }
    if (lane == 0) {
        v[row0]     = a0;
        v[row0 + 1] = a1;
        v[row0 + 2] = a2;
        v[row0 + 3] = a3;
    }
}

// N3: 2 tokens per wave: v/Wg float4 loads shared across both tokens (halves
// the 32KB-per-wave L2 re-read), 16 x-loads in flight. One x pass computes
// gate logits + both expert dots per token; s = gate * (dot[idx] + c[idx]).
__global__ __launch_bounds__(256) void k_token(const float* __restrict__ x,
                                               const float* __restrict__ Wg,
                                               const float* __restrict__ v,
                                               const float* __restrict__ c,
                                               float* __restrict__ s) {
    int gw   = (blockIdx.x * 256 + threadIdx.x) >> 6;   // 0..1023
    int lane = threadIdx.x & 63;
    const float* xp0 = x + (size_t)(2 * gw) * D_;
    const float* xp1 = xp0 + D_;
    float g0a = 0.f, g1a = 0.f, d0a = 0.f, d1a = 0.f;
    float g0b = 0.f, g1b = 0.f, d0b = 0.f, d1b = 0.f;
    #pragma unroll
    for (int k = 0; k < D_ / 256; ++k) {                // 8 iters
        int i = (lane + k * 64) * 4;
        float4 v0 = LD4(v + i);
        float4 v1 = LD4(v + D_ + i);
        float4 wa = LD4(Wg + 2 * i);                    // Wg[d=i..i+1, e=0..1]
        float4 wb = LD4(Wg + 2 * i + 4);
        float4 xa = LD4(xp0 + i);
        float4 xb = LD4(xp1 + i);
        g0a += xa.x * wa.x + xa.y * wa.z + xa.z * wb.x + xa.w * wb.z;
        g1a += xa.x * wa.y + xa.y * wa.w + xa.z * wb.y + xa.w * wb.w;
        d0a += xa.x * v0.x + xa.y * v0.y + xa.z * v0.z + xa.w * v0.w;
        d1a += xa.x * v1.x + xa.y * v1.y + xa.z * v1.z + xa.w * v1.w;
        g0b += xb.x * wa.x + xb.y * wa.z + xb.z * wb.x + xb.w * wb.z;
        g1b += xb.x * wa.y + xb.y * wa.w + xb.z * wb.y + xb.w * wb.w;
        d0b += xb.x * v0.x + xb.y * v0.y + xb.z * v0.z + xb.w * v0.w;
        d1b += xb.x * v1.x + xb.y * v1.y + xb.z * v1.z + xb.w * v1.w;
    }
    #pragma unroll
    for (int o = 32; o > 0; o >>= 1) {
        g0a += __shfl_down(g0a, o, 64);
        g1a += __shfl_down(g1a, o, 64);
        d0a += __shfl_down(d0a, o, 64);
        d1a += __shfl_down(d1a, o, 64);
        g0b += __shfl_down(g0b, o, 64);
        g1b += __shfl_down(g1b, o, 64);
        d0b += __shfl_down(d0b, o, 64);
        d1b += __shfl_down(d1b, o, 64);
    }
    if (lane == 0) {
        {
            int e = (g1a > g0a) ? 1 : 0;                // argmax, first index on tie
            float m  = fmaxf(g0a, g1a);
            float p0 = expf(g0a - m), p1 = expf(g1a - m);
            float gate = ((e == 0) ? p0 : p1) / (p0 + p1);
            float dot  = (e == 0) ? d0a : d1a;
            s[2 * gw] = gate * (dot + c[e]);
        }
        {
            int e = (g1b > g0b) ? 1 : 0;
            float m  = fmaxf(g0b, g1b);
            float p0 = expf(g0b - m), p1 = expf(g1b - m);
            float gate = ((e == 0) ? p0 : p1) / (p0 + p1);
            float dot  = (e == 0) ? d0b : d1b;
            s[2 * gw + 1] = gate * (dot + c[e]);
        }
    }
}

// N4: out[b,t] = s[b,t] - max_t - log(sum_t exp(s - max_t)). One block per b.
__global__ void k_lsm(const float* __restrict__ s, float* __restrict__ out) {
    __shared__ float lds[8];
    int b = blockIdx.x;
    int t = threadIdx.x;                        // 512 threads, 8 waves
    int lane = t & 63, wid = t >> 6;
    float val = s[b * T_ + t];

    float m = val;
    #pragma unroll
    for (int o = 1; o < 64; o <<= 1) m = fmaxf(m, __shfl_xor(m, o, 64));
    if (lane == 0) lds[wid] = m;
    __syncthreads();
    m = lds[0];
    #pragma unroll
    for (int w = 1; w < 8; ++w) m = fmaxf(m, lds[w]);
    __syncthreads();

    float ex = expf(val - m);
    float sum = ex;
    #pragma unroll
    for (int o = 1; o < 64; o <<= 1) sum += __shfl_xor(sum, o, 64);
    if (lane == 0) lds[wid] = sum;
    __syncthreads();
    sum = 0.f;
    #pragma unroll
    for (int w = 0; w < 8; ++w) sum += lds[w];

    out[b * T_ + t] = val - m - logf(sum);
}

extern "C" void kernel_launch(void* const* d_in, const int* in_sizes, int n_in,
                              void* d_out, int out_size, void* d_ws, size_t ws_size,
                              hipStream_t stream) {
    (void)in_sizes; (void)n_in; (void)out_size; (void)ws_size;
    const float* x  = (const float*)d_in[0];
    const float* Wg = (const float*)d_in[1];
    const float* W1 = (const float*)d_in[2];
    const float* b1 = (const float*)d_in[3];
    const float* W2 = (const float*)d_in[4];
    const float* b2 = (const float*)d_in[5];
    float* out = (float*)d_out;

    float* ws  = (float*)d_ws;
    float* w2s = ws;                    // [E,H]  2048 floats
    float* v   = ws + 2048;             // [E,D]  4096 floats
    float* c   = ws + 6144;             // [E]    2 floats
    float* s   = ws + 6160;             // [B,T]  2048 floats, 16B-aligned

    k_w2sum<<<256, 256, 0, stream>>>(W2, w2s);
    k_vred <<<258, 256, 0, stream>>>(W1, w2s, b1, b2, v, c);
    k_token<<<256, 256, 0, stream>>>(x, Wg, v, c, s);
    k_lsm  <<<B_,  512, 0, stream>>>(s, out);
}

// Round 10
// 23.242 us; speedup vs baseline: 1.5804x; 1.1116x over previous
//
#include <hip/hip_runtime.h>
#include <math.h>

#define B_ 4
#define T_ 512
#define D_ 2048
#define H_ 1024
#define E_ 2

#define LD4(p) (*reinterpret_cast<const float4*>(p))

// Lessons (measured, this session):
//  R2: __threadfence => buffer_wbl2/inv cache maintenance, +38us. Never.
//  R4: spinning on an RMW'd line => ownership ping-pong, ~20us/barrier. Never.
//  R5: 512 same-line fetch_adds serialize (~15ns each), +7us. Never.
//  R6: even polite store-array grid barriers cost ~17us. No grid sync, period.
//  R8: splitting the x-pass into 32-float slivers (partials scheme) wrecks
//      coalescing on the dominant stream: +13.5us. Keep unit-stride fat rows.
//  R9: fatter waves (4 rows/wave) halve wave count -> latency-hiding loss,
//      +2.6us. These kernels are latency-bound on L3-resident data; TLP wins.
//  => This file = R7 config, the measured optimum (23.2us): 4-node graph,
//     2 rows/wave weight passes, 1 token/wave x pass.

__device__ __forceinline__ float waveReduceSum(float v) {
    #pragma unroll
    for (int o = 32; o > 0; o >>= 1) v += __shfl_down(v, o, 64);
    return v;
}

// N1: w2s[row] = sum_d W2[row,d], row = e*H+h. 2 rows per wave, 256 blocks.
__global__ __launch_bounds__(256) void k_w2sum(const float* __restrict__ W2,
                                               float* __restrict__ w2s) {
    int gw   = (blockIdx.x * 256 + threadIdx.x) >> 6;   // 0..1023
    int lane = threadIdx.x & 63;
    const float* p0 = W2 + (size_t)(2 * gw) * D_;
    const float* p1 = p0 + D_;
    float a0 = 0.f, a1 = 0.f;
    #pragma unroll
    for (int k = 0; k < D_ / 256; ++k) {                // 8 float4 per lane per row
        float4 u = LD4(p0 + (lane + k * 64) * 4);
        float4 w = LD4(p1 + (lane + k * 64) * 4);
        a0 += (u.x + u.y) + (u.z + u.w);
        a1 += (w.x + w.y) + (w.z + w.w);
    }
    #pragma unroll
    for (int o = 32; o > 0; o >>= 1) {
        a0 += __shfl_down(a0, o, 64);
        a1 += __shfl_down(a1, o, 64);
    }
    if (lane == 0) {
        w2s[2 * gw]     = a0;
        w2s[2 * gw + 1] = a1;
    }
}

// N2: v[e,d] = sum_h W1[e,d,h]*w2s[e,h]. 2 rows per wave (pair never straddles
// the expert boundary). Blocks 512/513 compute c[e] = b1.w2s + sum(b2).
__global__ __launch_bounds__(256) void k_vred(const float* __restrict__ W1,
                                              const float* __restrict__ w2s,
                                              const float* __restrict__ b1,
                                              const float* __restrict__ b2,
                                              float* __restrict__ v,
                                              float* __restrict__ c) {
    if (blockIdx.x >= 512) {
        __shared__ float lds[4];
        int e = blockIdx.x - 512;
        float acc = 0.f;
        for (int i = threadIdx.x; i < H_; i += 256) acc += b1[e * H_ + i] * w2s[e * H_ + i];
        for (int i = threadIdx.x; i < D_; i += 256) acc += b2[e * D_ + i];
        acc = waveReduceSum(acc);
        if ((threadIdx.x & 63) == 0) lds[threadIdx.x >> 6] = acc;
        __syncthreads();
        if (threadIdx.x == 0) c[e] = lds[0] + lds[1] + lds[2] + lds[3];
        return;
    }
    int gw   = (blockIdx.x * 256 + threadIdx.x) >> 6;   // 0..2047
    int lane = threadIdx.x & 63;
    int row0 = 2 * gw;                                  // 0..4094 (even)
    int e    = row0 >> 11;                              // row / D_
    const float* p0 = W1 + (size_t)row0 * H_;
    const float* p1 = p0 + H_;
    const float* w  = w2s + e * H_;
    float a0 = 0.f, a1 = 0.f;
    #pragma unroll
    for (int k = 0; k < H_ / 256; ++k) {                // 4 float4 per lane per row
        float4 wa = LD4(w  + (lane + k * 64) * 4);
        float4 u  = LD4(p0 + (lane + k * 64) * 4);
        float4 t  = LD4(p1 + (lane + k * 64) * 4);
        a0 += u.x * wa.x + u.y * wa.y + u.z * wa.z + u.w * wa.w;
        a1 += t.x * wa.x + t.y * wa.y + t.z * wa.z + t.w * wa.w;
    }
    #pragma unroll
    for (int o = 32; o > 0; o >>= 1) {
        a0 += __shfl_down(a0, o, 64);
        a1 += __shfl_down(a1, o, 64);
    }
    if (lane == 0) {
        v[row0]     = a0;
        v[row0 + 1] = a1;
    }
}

// N3: one wave per token: gate logits + both expert dots in one x pass,
// s[bt] = gate * (dot[idx] + c[idx]).  No fences, no atomics.
__global__ __launch_bounds__(256) void k_token(const float* __restrict__ x,
                                               const float* __restrict__ Wg,
                                               const float* __restrict__ v,
                                               const float* __restrict__ c,
                                               float* __restrict__ s) {
    int lane = threadIdx.x & 63;
    int bt   = (blockIdx.x * 256 + threadIdx.x) >> 6;   // 0..2047
    const float* xp = x + (size_t)bt * D_;
    float g0 = 0.f, g1 = 0.f, d0 = 0.f, d1 = 0.f;
    #pragma unroll
    for (int k = 0; k < D_ / 256; ++k) {                // 8 iterations
        int i = (lane + k * 64) * 4;
        float4 xv = LD4(xp + i);
        float4 v0 = LD4(v + i);
        float4 v1 = LD4(v + D_ + i);
        float4 wa = LD4(Wg + 2 * i);                    // Wg[d=i..i+1, e=0..1]
        float4 wb = LD4(Wg + 2 * i + 4);
        g0 += xv.x * wa.x + xv.y * wa.z + xv.z * wb.x + xv.w * wb.z;
        g1 += xv.x * wa.y + xv.y * wa.w + xv.z * wb.y + xv.w * wb.w;
        d0 += xv.x * v0.x + xv.y * v0.y + xv.z * v0.z + xv.w * v0.w;
        d1 += xv.x * v1.x + xv.y * v1.y + xv.z * v1.z + xv.w * v1.w;
    }
    #pragma unroll
    for (int o = 32; o > 0; o >>= 1) {
        g0 += __shfl_down(g0, o, 64);
        g1 += __shfl_down(g1, o, 64);
        d0 += __shfl_down(d0, o, 64);
        d1 += __shfl_down(d1, o, 64);
    }
    if (lane == 0) {
        int e = (g1 > g0) ? 1 : 0;                      // argmax, first index on tie
        float m  = fmaxf(g0, g1);
        float p0 = expf(g0 - m), p1 = expf(g1 - m);
        float gate = ((e == 0) ? p0 : p1) / (p0 + p1);
        float dot  = (e == 0) ? d0 : d1;
        s[bt] = gate * (dot + c[e]);
    }
}

// N4: out[b,t] = s[b,t] - max_t - log(sum_t exp(s - max_t)). One block per b.
__global__ void k_lsm(const float* __restrict__ s, float* __restrict__ out) {
    __shared__ float lds[8];
    int b = blockIdx.x;
    int t = threadIdx.x;                        // 512 threads, 8 waves
    int lane = t & 63, wid = t >> 6;
    float val = s[b * T_ + t];

    float m = val;
    #pragma unroll
    for (int o = 1; o < 64; o <<= 1) m = fmaxf(m, __shfl_xor(m, o, 64));
    if (lane == 0) lds[wid] = m;
    __syncthreads();
    m = lds[0];
    #pragma unroll
    for (int w = 1; w < 8; ++w) m = fmaxf(m, lds[w]);
    __syncthreads();

    float ex = expf(val - m);
    float sum = ex;
    #pragma unroll
    for (int o = 1; o < 64; o <<= 1) sum += __shfl_xor(sum, o, 64);
    if (lane == 0) lds[wid] = sum;
    __syncthreads();
    sum = 0.f;
    #pragma unroll
    for (int w = 0; w < 8; ++w) sum += lds[w];

    out[b * T_ + t] = val - m - logf(sum);
}

extern "C" void kernel_launch(void* const* d_in, const int* in_sizes, int n_in,
                              void* d_out, int out_size, void* d_ws, size_t ws_size,
                              hipStream_t stream) {
    (void)in_sizes; (void)n_in; (void)out_size; (void)ws_size;
    const float* x  = (const float*)d_in[0];
    const float* Wg = (const float*)d_in[1];
    const float* W1 = (const float*)d_in[2];
    const float* b1 = (const float*)d_in[3];
    const float* W2 = (const float*)d_in[4];
    const float* b2 = (const float*)d_in[5];
    float* out = (float*)d_out;

    float* ws  = (float*)d_ws;
    float* w2s = ws;                    // [E,H]  2048 floats
    float* v   = ws + 2048;             // [E,D]  4096 floats
    float* c   = ws + 6144;             // [E]    2 floats
    float* s   = ws + 6160;             // [B,T]  2048 floats, 16B-aligned

    k_w2sum<<<256, 256, 0, stream>>>(W2, w2s);
    k_vred <<<514, 256, 0, stream>>>(W1, w2s, b1, b2, v, c);
    k_token<<<512, 256, 0, stream>>>(x, Wg, v, c, s);
    k_lsm  <<<B_,  512, 0, stream>>>(s, out);
}